// Round 4
// baseline (1898.694 us; speedup 1.0000x reference)
//
#include <hip/hip_runtime.h>

// LSTM_27152783245909 — persistent-recurrence LSTM for MI355X (gfx950)
// R4: collapsed the per-step phase chain. K=1536 split 8 ways (one slice per
// wave, all 64 gate-cols): A-fragments are wave-unique -> direct sc0/sc1
// loads into MFMA operands (no LDS h-staging, no nh duplication). ONE
// __syncthreads per step (gpart double-buffered). Only wave 0 polls MALL
// flags; others spin on an LDS token. Flag publish via LDS arrival counter
// (no trailing sync). x-fragments prefetched before the poll.

#define T_ 256

typedef __attribute__((ext_vector_type(8))) short bf16x8;
typedef __attribute__((ext_vector_type(4))) float floatx4;
typedef __attribute__((ext_vector_type(4))) int intx4;
typedef __attribute__((ext_vector_type(4))) unsigned uintx4;

__device__ __forceinline__ unsigned short f2bf(float f) {
  unsigned u = __builtin_bit_cast(unsigned, f);
  u += 0x7FFFu + ((u >> 16) & 1u);   // round-nearest-even
  return (unsigned short)(u >> 16);
}

__device__ __forceinline__ float sigm(float x) { return 1.0f / (1.0f + __expf(-x)); }

// ---------------- W_out fp32 -> bf16 (512x1024) ----------------
__global__ void cvt_w(const float* __restrict__ w, unsigned short* __restrict__ o) {
  const size_t g = (size_t)blockIdx.x * 256 + threadIdx.x;
  const float* s = w + g * 8;
  bf16x8 v;
#pragma unroll
  for (int i = 0; i < 8; ++i) v[i] = (short)f2bf(s[i]);
  *(bf16x8*)(o + g * 8) = v;
}

// ---------------- x[B=64, I=512, T=256] fp32 -> xT[T,B,I] bf16 ----------------
__global__ void transpose_x(const float* __restrict__ x, unsigned short* __restrict__ xT) {
  __shared__ float tile[32][33];
  const int b = blockIdx.z, i0 = blockIdx.y * 32, t0 = blockIdx.x * 32;
  const int tx = threadIdx.x & 31, ty = threadIdx.x >> 5;
#pragma unroll
  for (int p = 0; p < 4; ++p) {
    const int i = ty + p * 8;
    tile[i][tx] = x[((size_t)b * 512 + i0 + i) * 256 + t0 + tx];
  }
  __syncthreads();
#pragma unroll
  for (int p = 0; p < 4; ++p) {
    const int t = ty + p * 8;
    xT[((size_t)(t0 + t) * 64 + b) * 512 + i0 + tx] = f2bf(tile[tx][t]);
  }
}

// ---------------- persistent recurrence ----------------
// 256 blocks x 512 thr, 1 block/CU. Block (mg,ng): batch rows [16mg,16mg+16),
// units [16ng,16ng+16) (gate cols g*1024+16ng+j, g=0..3). Wave w owns K-slice
// ksteps {w, w+8, ..., w+40} of 48 (i 0..3 -> h region, i 4..5 -> x region),
// computing all 4 gate col-tiles -> 4 independent acc chains, 24 MFMA/wave.
// Weights: bfrag[4][6] = 96 VGPR/lane. Partials: gpartT[2][8][64][17] LDS.
__global__ __launch_bounds__(512, 2) void lstm_rec(
    const float* __restrict__ Whh, const float* __restrict__ Wih,
    const float* __restrict__ bih, const float* __restrict__ bhh,
    const float* __restrict__ h0, const float* __restrict__ c0,
    const unsigned short* __restrict__ xT,
    unsigned short* __restrict__ hbuf,   // [2][64][1024] bf16 (sc0/sc1 only)
    unsigned short* __restrict__ call,   // [256][64][1024] bf16 (normal cached)
    unsigned* __restrict__ flags)        // [4][64] dwords (block-level)
{
  const int tid = threadIdx.x;
  const int lane = tid & 63;
  const int w = tid >> 6;            // 0..7 K-slice
  const int mg = blockIdx.x & 3, ng = blockIdx.x >> 2;
  const int l15 = lane & 15, lq = lane >> 4;
  const int row = mg * 16 + l15;     // A-fragment batch row

  unsigned* grpflags = flags + mg * 64;
  unsigned* myflag   = grpflags + ng;
  const unsigned* pollp = grpflags + (lane & 15) * 4;   // 16 uint4 covers 64 dwords

  __shared__ float gpartT[2][8][64][17];  // [buf][kslice][col][m(+1 pad)]
  __shared__ unsigned token;              // LDS step token (wave0 -> others)
  __shared__ unsigned scnt;               // arrival counter for flag publish

  // persistent B fragments: 4 gates x 6 ksteps = 96 VGPRs/lane
  bf16x8 bfrag[4][6];
#pragma unroll
  for (int g = 0; g < 4; ++g) {
    const int ncol = g * 1024 + ng * 16 + l15;
#pragma unroll
    for (int i = 0; i < 6; ++i) {
      const int gk = w + 8 * i;
      const float* s = (gk < 32) ? (Whh + (size_t)ncol * 1024 + gk * 32 + lq * 8)
                                 : (Wih + (size_t)ncol * 512 + (gk - 32) * 32 + lq * 8);
      bf16x8 v;
#pragma unroll
      for (int e = 0; e < 8; ++e) v[e] = (short)f2bf(s[e]);
      bfrag[g][i] = v;
    }
  }

  // per-thread elementwise state (waves 0..3): one (batch m, unit j) cell
  const int m_loc = tid >> 4, j = tid & 15;
  const int row_g = mg * 16 + m_loc;
  const int unit = ng * 16 + j;
  float c_reg = 0.f, bs0 = 0.f, bs1 = 0.f, bs2 = 0.f, bs3 = 0.f;

  if (tid == 0) { token = 0u; scnt = 0u; }
  __syncthreads();

  if (tid < 256) {
    c_reg = c0[unit];
    bs0 = bih[unit] + bhh[unit];
    bs1 = bih[1024 + unit] + bhh[1024 + unit];
    bs2 = bih[2048 + unit] + bhh[2048 + unit];
    bs3 = bih[3072 + unit] + bhh[3072 + unit];
    unsigned short* hp = hbuf + 65536 + row_g * 1024 + unit;
    const unsigned hv = f2bf(h0[unit]);
    asm volatile("global_store_short %0, %1, off sc0 sc1\n\t"
                 "s_waitcnt vmcnt(0)" :: "v"(hp), "v"(hv) : "memory");
    if (lane == 0) {
      const unsigned old = atomicAdd(&scnt, 1u);
      if (old == 3u) {                     // last of 4 waves: all 16 rows visible
        const unsigned one = 1u;
        asm volatile("global_store_dword %0, %1, off sc0 sc1"
                     :: "v"(myflag), "v"(one) : "memory");
      }
    }
  }

  for (int t = 0; t < T_; ++t) {
    // ---- prefetch x A-fragments (independent of h; latency hides in wait) ----
    const unsigned short* bx = xT + ((size_t)t * 64 + row) * 512 + lq * 8;
    intx4 x4, x5;
    asm volatile("global_load_dwordx4 %0, %2, off\n\t"
                 "global_load_dwordx4 %1, %3, off"
                 : "=v"(x4), "=v"(x5)
                 : "v"(bx + w * 32), "v"(bx + (w + 8) * 32) : "memory");

    // ---- wait for h_{t-1}: wave 0 polls MALL flags, others spin LDS token ----
    const unsigned tgt = (unsigned)(t + 1);
    if (w == 0) {
      uintx4 f;
      do {
        asm volatile("global_load_dwordx4 %0, %1, off sc0 sc1\n\t"
                     "s_waitcnt vmcnt(0)"
                     : "=v"(f) : "v"(pollp) : "memory");
      } while (!__all(f[0] >= tgt && f[1] >= tgt && f[2] >= tgt && f[3] >= tgt));
      __hip_atomic_store(&token, tgt, __ATOMIC_RELAXED, __HIP_MEMORY_SCOPE_WORKGROUP);
    } else {
      while (__hip_atomic_load(&token, __ATOMIC_RELAXED,
                               __HIP_MEMORY_SCOPE_WORKGROUP) < tgt) {}
    }

    // ---- direct coherent h A-loads (wave-unique; no LDS staging) ----
    const unsigned short* bh = hbuf + ((t + 1) & 1) * 65536 + (size_t)row * 1024 + lq * 8;
    intx4 h0v, h1v, h2v, h3v;
    asm volatile(
        "global_load_dwordx4 %0, %4, off sc0 sc1\n\t"
        "global_load_dwordx4 %1, %5, off sc0 sc1\n\t"
        "global_load_dwordx4 %2, %6, off sc0 sc1\n\t"
        "global_load_dwordx4 %3, %7, off sc0 sc1\n\t"
        "s_waitcnt vmcnt(0)"
        : "=v"(h0v), "=v"(h1v), "=v"(h2v), "=v"(h3v)
        : "v"(bh + w * 32), "v"(bh + (w + 8) * 32),
          "v"(bh + (w + 16) * 32), "v"(bh + (w + 24) * 32) : "memory");

    bf16x8 a[6];
    a[0] = __builtin_bit_cast(bf16x8, h0v);
    a[1] = __builtin_bit_cast(bf16x8, h1v);
    a[2] = __builtin_bit_cast(bf16x8, h2v);
    a[3] = __builtin_bit_cast(bf16x8, h3v);
    a[4] = __builtin_bit_cast(bf16x8, x4);
    a[5] = __builtin_bit_cast(bf16x8, x5);

    floatx4 zero = {0.f, 0.f, 0.f, 0.f};
    floatx4 acc[4] = {zero, zero, zero, zero};
#pragma unroll
    for (int i = 0; i < 6; ++i)
#pragma unroll
      for (int g = 0; g < 4; ++g)
        acc[g] = __builtin_amdgcn_mfma_f32_16x16x32_bf16(a[i], bfrag[g][i], acc[g], 0, 0, 0);

    // ---- partials to LDS (transposed: b128 per gate) ----
#pragma unroll
    for (int g = 0; g < 4; ++g)
      *(floatx4*)&gpartT[t & 1][w][g * 16 + l15][lq * 4] = acc[g];
    __syncthreads();   // the ONLY barrier per step

    // ---- gate reduce + elementwise (waves 0..3) ----
    if (tid < 256) {
      float gi = bs0, gf = bs1, gg = bs2, go = bs3;
#pragma unroll
      for (int q = 0; q < 8; ++q) {
        gi += gpartT[t & 1][q][j][m_loc];
        gf += gpartT[t & 1][q][16 + j][m_loc];
        gg += gpartT[t & 1][q][32 + j][m_loc];
        go += gpartT[t & 1][q][48 + j][m_loc];
      }
      const float iv = sigm(gi), fv = sigm(gf), gv = tanhf(gg), ov = sigm(go);
      c_reg = fv * c_reg + iv * gv;
      const float hv = ov * tanhf(c_reg);
      call[((size_t)t * 64 + row_g) * 1024 + unit] = f2bf(c_reg);
      unsigned short* hp = hbuf + (t & 1) * 65536 + row_g * 1024 + unit;
      const unsigned hb = f2bf(hv);
      asm volatile("global_store_short %0, %1, off sc0 sc1\n\t"
                   "s_waitcnt vmcnt(0)" :: "v"(hp), "v"(hb) : "memory");
      if (lane == 0) {
        const unsigned old = atomicAdd(&scnt, 1u);
        if (old == (unsigned)(4 * t + 7)) {   // last arrival of this step
          const unsigned val = (unsigned)(t + 2);
          asm volatile("global_store_dword %0, %1, off sc0 sc1"
                       :: "v"(myflag), "v"(val) : "memory");
        }
      }
    }
    // no trailing sync: gpartT double-buffered; waves gate on token/flags
  }
}

// ---------------- output head: logits + softmax, fully parallel over t ----------------
__global__ __launch_bounds__(256, 1) void lstm_head(
    const unsigned short* __restrict__ call,
    const unsigned short* __restrict__ wout,
    const float* __restrict__ bout,
    float* __restrict__ out)
{
  const int tb = blockIdx.x;
  const int lane = threadIdx.x & 63;
  const int wv = threadIdx.x >> 6;
  const int l15 = lane & 15, lq = lane >> 4;

  __shared__ float sred[2][4][64];

  floatx4 zero = {0.f, 0.f, 0.f, 0.f};
  floatx4 acc[4][8];
#pragma unroll
  for (int mt = 0; mt < 4; ++mt)
#pragma unroll
    for (int nt = 0; nt < 8; ++nt) acc[mt][nt] = zero;

  const unsigned short* abase = call + ((size_t)tb * 64 + l15) * 1024 + lq * 8;
  const unsigned short* bbase = wout + ((size_t)(wv * 128 + l15)) * 1024 + lq * 8;

#pragma unroll 2
  for (int ks = 0; ks < 32; ++ks) {
    bf16x8 a[4];
#pragma unroll
    for (int mt = 0; mt < 4; ++mt)
      a[mt] = *(const bf16x8*)(abase + (size_t)mt * 16 * 1024 + ks * 32);
#pragma unroll
    for (int nt = 0; nt < 8; ++nt) {
      const bf16x8 b = *(const bf16x8*)(bbase + (size_t)nt * 16 * 1024 + ks * 32);
#pragma unroll
      for (int mt = 0; mt < 4; ++mt)
        acc[mt][nt] = __builtin_amdgcn_mfma_f32_16x16x32_bf16(a[mt], b, acc[mt][nt], 0, 0, 0);
    }
  }

#pragma unroll
  for (int nt = 0; nt < 8; ++nt) {
    const float bo = bout[wv * 128 + nt * 16 + l15];
#pragma unroll
    for (int mt = 0; mt < 4; ++mt)
#pragma unroll
      for (int r = 0; r < 4; ++r) acc[mt][nt][r] += bo;
  }

  float rmax[4][4];
#pragma unroll
  for (int mt = 0; mt < 4; ++mt)
#pragma unroll
    for (int r = 0; r < 4; ++r) {
      float m = acc[mt][0][r];
#pragma unroll
      for (int nt = 1; nt < 8; ++nt) m = fmaxf(m, acc[mt][nt][r]);
      m = fmaxf(m, __shfl_xor(m, 1, 64));
      m = fmaxf(m, __shfl_xor(m, 2, 64));
      m = fmaxf(m, __shfl_xor(m, 4, 64));
      m = fmaxf(m, __shfl_xor(m, 8, 64));
      rmax[mt][r] = m;
    }
  if (l15 == 0) {
#pragma unroll
    for (int mt = 0; mt < 4; ++mt)
#pragma unroll
      for (int r = 0; r < 4; ++r) sred[0][wv][mt * 16 + lq * 4 + r] = rmax[mt][r];
  }
  __syncthreads();
  float gmax[4][4], rsum[4][4];
#pragma unroll
  for (int mt = 0; mt < 4; ++mt)
#pragma unroll
    for (int r = 0; r < 4; ++r) {
      const int rw = mt * 16 + lq * 4 + r;
      gmax[mt][r] = fmaxf(fmaxf(sred[0][0][rw], sred[0][1][rw]),
                          fmaxf(sred[0][2][rw], sred[0][3][rw]));
      rsum[mt][r] = 0.f;
    }
#pragma unroll
  for (int mt = 0; mt < 4; ++mt)
#pragma unroll
    for (int nt = 0; nt < 8; ++nt)
#pragma unroll
      for (int r = 0; r < 4; ++r) {
        const float e = __expf(acc[mt][nt][r] - gmax[mt][r]);
        acc[mt][nt][r] = e;
        rsum[mt][r] += e;
      }
#pragma unroll
  for (int mt = 0; mt < 4; ++mt)
#pragma unroll
    for (int r = 0; r < 4; ++r) {
      float s = rsum[mt][r];
      s += __shfl_xor(s, 1, 64);
      s += __shfl_xor(s, 2, 64);
      s += __shfl_xor(s, 4, 64);
      s += __shfl_xor(s, 8, 64);
      rsum[mt][r] = s;
    }
  if (l15 == 0) {
#pragma unroll
    for (int mt = 0; mt < 4; ++mt)
#pragma unroll
      for (int r = 0; r < 4; ++r) sred[1][wv][mt * 16 + lq * 4 + r] = rsum[mt][r];
  }
  __syncthreads();
#pragma unroll
  for (int mt = 0; mt < 4; ++mt)
#pragma unroll
    for (int r = 0; r < 4; ++r) {
      const int rw = mt * 16 + lq * 4 + r;
      const float inv = 1.0f / (sred[1][0][rw] + sred[1][1][rw] +
                                sred[1][2][rw] + sred[1][3][rw]);
      float* orow = out + ((size_t)tb * 64 + rw) * 512 + wv * 128 + l15;
#pragma unroll
      for (int nt = 0; nt < 8; ++nt) orow[nt * 16] = acc[mt][nt][r] * inv;
    }
}

// ---------------- launch ----------------
extern "C" void kernel_launch(void* const* d_in, const int* in_sizes, int n_in,
                              void* d_out, int out_size, void* d_ws, size_t ws_size,
                              hipStream_t stream) {
  const float* x    = (const float*)d_in[0];
  const float* Wih  = (const float*)d_in[1];
  const float* Whh  = (const float*)d_in[2];
  const float* bih  = (const float*)d_in[3];
  const float* bhh  = (const float*)d_in[4];
  const float* Wout = (const float*)d_in[5];
  const float* bout = (const float*)d_in[6];
  const float* h0   = (const float*)d_in[7];
  const float* c0   = (const float*)d_in[8];
  float* out = (float*)d_out;

  char* ws = (char*)d_ws;
  unsigned* flags       = (unsigned*)(ws + 0);                  //     1 KB
  unsigned short* hbuf  = (unsigned short*)(ws + 4096);         //   256 KB
  unsigned short* woutb = (unsigned short*)(ws + 266240);       //     1 MB
  unsigned short* xT    = (unsigned short*)(ws + 1314816);      //    16 MB
  unsigned short* call  = (unsigned short*)(ws + 18092032);     //    32 MB

  hipMemsetAsync(flags, 0, 1024, stream);
  cvt_w<<<256, 256, 0, stream>>>(Wout, woutb);
  transpose_x<<<dim3(8, 16, 64), 256, 0, stream>>>(x, xT);
  lstm_rec<<<256, 512, 0, stream>>>(Whh, Wih, bih, bhh, h0, c0, xT, hbuf, call, flags);
  lstm_head<<<256, 256, 0, stream>>>(call, woutb, bout, out);
}